// Round 4
// baseline (464.173 us; speedup 1.0000x reference)
//
#include <hip/hip_runtime.h>

// Problem constants: B=32 graphs, N=1024 nodes/graph, F=64, D=128, DEG=8
#define E_TOTAL 262144
#define NGRAPH  32
#define EPG     8192
#define EPS_BN  1e-5f
#define NBLK    256
#define NTHR    1024

__device__ __forceinline__ float lrelu(float x){ return x > 0.f ? x : 0.2f * x; }

// LDS union across phases; max member = 32 KB -> >=2 blocks/CU capacity, grid=256 co-resident.
struct SM {
  union {
    struct { float Ws[64 * 128]; } g;                         // 32 KB (gemm W chunk)
    struct { int cnt[1024]; int pos[1024]; int wsum[16]; } c; // 8.3 KB (csr)
    struct { float4 bnred[16 * 64]; } b;                      // 16 KB (gat bn reduce)
  };
};

// ---- device-scope grid barrier (all NBLK blocks co-resident by construction) ----
__device__ __forceinline__ void grid_barrier(unsigned* bar){
  __syncthreads();
  if (threadIdx.x == 0){
    __threadfence();  // release: drain this block's stores to coherence point
    unsigned arr = atomicAdd(bar, 1u);                      // device-scope
    unsigned target = (arr / NBLK + 1u) * NBLK;
    while (__hip_atomic_load(bar, __ATOMIC_ACQUIRE, __HIP_MEMORY_SCOPE_AGENT) < target)
      __builtin_amdgcn_s_sleep(8);
    __threadfence();  // acquire: invalidate stale cache lines
  }
  __syncthreads();
}

// ---- GEMM + attention terms: C = bn(A)@W, es/ed via wave shuffle-reduce ----
// 64-row tiles; wave rg handles rows rg*4..rg*4+3; lane = channel pair.
// A fragment in registers (lane l holds A[row][l] (+[l+64])), broadcast via __shfl.
template<int K>
__device__ void dev_gemm(SM& sm, const float* __restrict__ A, const float* __restrict__ W,
                         const float* __restrict__ bnsums, float invM,
                         const float* __restrict__ a_s, const float* __restrict__ a_d,
                         float* __restrict__ C, float* __restrict__ es, float* __restrict__ ed,
                         int M, int workerId, int nWorkers){
  int tid = threadIdx.x, lane = tid & 63, rg = tid >> 6;
  float mu0 = 0.f, rs0 = 1.f, mu1 = 0.f, rs1 = 1.f;
  if (bnsums){
    mu0 = bnsums[lane] * invM;
    float v0 = bnsums[K + lane] * invM - mu0 * mu0;
    rs0 = rsqrtf(v0 + EPS_BN);
    if (K > 64){
      mu1 = bnsums[lane + 64] * invM;
      float v1 = bnsums[K + lane + 64] * invM - mu1 * mu1;
      rs1 = rsqrtf(v1 + EPS_BN);
    }
  }
  float2 as2 = ((const float2*)a_s)[lane];
  float2 ad2 = ((const float2*)a_d)[lane];
  int ntiles = M >> 6;
  for (int t = workerId; t < ntiles; t += nWorkers){
    int row0 = t << 6;
    float a0[4], a1[4];
    #pragma unroll
    for (int i = 0; i < 4; ++i){
      int r = row0 + rg * 4 + i;
      a0[i] = (A[(size_t)r * K + lane] - mu0) * rs0;
      if (K > 64) a1[i] = (A[(size_t)r * K + lane + 64] - mu1) * rs1;
    }
    float2 acc[4] = {};
    for (int k0 = 0; k0 < K; k0 += 64){
      __syncthreads();
      for (int i = tid; i < 8192; i += NTHR)
        sm.g.Ws[i] = W[(size_t)(k0 + (i >> 7)) * 128 + (i & 127)];
      __syncthreads();
      #pragma unroll 8
      for (int kk = 0; kk < 64; ++kk){
        float2 w = *(float2*)&sm.g.Ws[kk * 128 + lane * 2];
        #pragma unroll
        for (int i = 0; i < 4; ++i){
          float a = (k0 == 0) ? __shfl(a0[i], kk) : __shfl(a1[i], kk);
          acc[i].x = fmaf(a, w.x, acc[i].x);
          acc[i].y = fmaf(a, w.y, acc[i].y);
        }
      }
    }
    #pragma unroll
    for (int i = 0; i < 4; ++i){
      int r = row0 + rg * 4 + i;
      ((float2*)C)[(size_t)r * 64 + lane] = acc[i];
      float e1 = acc[i].x * as2.x + acc[i].y * as2.y;
      float e2 = acc[i].x * ad2.x + acc[i].y * ad2.y;
      #pragma unroll
      for (int o = 32; o; o >>= 1){ e1 += __shfl_xor(e1, o); e2 += __shfl_xor(e2, o); }
      if (lane == 0){ es[r] = e1; ed[r] = e2; }
    }
  }
}

// ---- per-graph counting sort by dst + inline dedupe-for-next-layer; one block/graph ----
__device__ void dev_csr(SM& sm, const int* __restrict__ src0, const int* __restrict__ dst0,
                        const unsigned char* __restrict__ maskIn,
                        int* __restrict__ csr_src, int* __restrict__ row_start,
                        int* __restrict__ row_cnt, int shift, int Npg,
                        unsigned char* __restrict__ maskOut, unsigned int* __restrict__ bitmap,
                        int shiftN, int log2NpgN, int g){
  int t = threadIdx.x;
  int ebase = g * EPG;
  unsigned int* bmg = nullptr;
  if (bitmap){
    int words = 1 << (2 * log2NpgN - 5);    // per-graph bitmap slice
    bmg = bitmap + (size_t)g * words;
    for (int i = t; i < words; i += NTHR) bmg[i] = 0;
  }
  if (t < Npg) sm.c.cnt[t] = 0;
  __syncthreads();
  unsigned keep = 0;
  #pragma unroll
  for (int k = 0; k < 8; ++k){
    int e = ebase + t + k * NTHR;
    int sv = src0[e], dv = dst0[e];
    bool act = maskIn ? (maskIn[e] != 0) : (sv != dv);
    if (act){
      keep |= (1u << k);
      atomicAdd(&sm.c.cnt[(dv >> shift) & (Npg - 1)], 1);
    }
    if (maskOut){
      unsigned char m2 = 0;
      if (act){
        int s2 = sv >> shiftN, d2 = dv >> shiftN;
        if (s2 != d2){
          int NpgN = 1 << log2NpgN;
          unsigned key = ((unsigned)(s2 & (NpgN - 1)) << log2NpgN) | (unsigned)(d2 & (NpgN - 1));
          unsigned bit = 1u << (key & 31u);
          unsigned old = atomicOr(&bmg[key >> 5], bit);
          m2 = (old & bit) ? 0 : 1;
        }
      }
      maskOut[e] = m2;
    }
  }
  __syncthreads();
  int c = (t < Npg) ? sm.c.cnt[t] : 0;
  int lane = t & 63, w = t >> 6;
  int v = c;
  #pragma unroll
  for (int o = 1; o < 64; o <<= 1){
    int u = __shfl_up(v, o);
    if (lane >= o) v += u;
  }
  if (lane == 63) sm.c.wsum[w] = v;
  __syncthreads();
  if (t == 0){
    int run = 0;
    #pragma unroll
    for (int i = 0; i < 16; ++i){ int x = sm.c.wsum[i]; sm.c.wsum[i] = run; run += x; }
  }
  __syncthreads();
  int excl = v - c + sm.c.wsum[w];
  if (t < Npg){
    sm.c.pos[t] = excl;
    row_start[g * Npg + t] = ebase + excl;
    row_cnt[g * Npg + t]   = c;
  }
  __syncthreads();
  #pragma unroll
  for (int k = 0; k < 8; ++k){
    if (keep & (1u << k)){
      int e = ebase + t + k * NTHR;
      int d = (dst0[e] >> shift) & (Npg - 1);
      int p = atomicAdd(&sm.c.pos[d], 1);
      csr_src[ebase + p] = src0[e] >> shift;
    }
  }
}

// ---- one GAT node (softmax over neighbors + self loop), returns relu(agg+bias) ----
__device__ float2 dev_gat_node(const float2* __restrict__ h2, const float* __restrict__ es,
                               const float* __restrict__ ed, const int* __restrict__ csr_src,
                               const int* __restrict__ row_start, const int* __restrict__ row_cnt,
                               float2 bv, int n, int lane){
  int start = row_start[n];
  int cnt   = row_cnt[n];
  float edn = ed[n];
  float selfl = lrelu(es[n] + edn);
  float m_l = -1e30f, d_l = 0.f;
  for (int c0 = 0; c0 < cnt; c0 += 64){
    int j = c0 + lane;
    if (j < cnt){
      int s = csr_src[start + j];
      float l = lrelu(es[s] + edn);
      float mn = fmaxf(m_l, l);
      d_l = d_l * __expf(m_l - mn) + __expf(l - mn);
      m_l = mn;
    }
  }
  #pragma unroll
  for (int o = 32; o; o >>= 1){
    float m2 = __shfl_xor(m_l, o), d2 = __shfl_xor(d_l, o);
    float mn = fmaxf(m_l, m2);
    d_l = d_l * __expf(m_l - mn) + d2 * __expf(m2 - mn);
    m_l = mn;
  }
  float mf  = fmaxf(m_l, selfl);
  float den = d_l * __expf(m_l - mf) + __expf(selfl - mf);
  float sw  = __expf(selfl - mf);
  float2 hv = h2[(size_t)n * 64 + lane];
  float2 acc; acc.x = sw * hv.x; acc.y = sw * hv.y;
  for (int c0 = 0; c0 < cnt; c0 += 64){
    int j = c0 + lane;
    int s_j = 0; float w_j = 0.f;
    if (j < cnt){
      s_j = csr_src[start + j];
      w_j = __expf(lrelu(es[s_j] + edn) - mf);
    }
    int rem = min(64, cnt - c0);
    int k = 0;
    for (; k + 8 <= rem; k += 8){
      int ss[8]; float ww[8]; float2 hh[8];
      #pragma unroll
      for (int i = 0; i < 8; ++i){ ss[i] = __shfl(s_j, k + i); ww[i] = __shfl(w_j, k + i); }
      #pragma unroll
      for (int i = 0; i < 8; ++i) hh[i] = h2[(size_t)ss[i] * 64 + lane];
      #pragma unroll
      for (int i = 0; i < 8; ++i){
        acc.x = fmaf(ww[i], hh[i].x, acc.x);
        acc.y = fmaf(ww[i], hh[i].y, acc.y);
      }
    }
    for (; k < rem; ++k){
      int s = __shfl(s_j, k); float w = __shfl(w_j, k);
      float2 hh = h2[(size_t)s * 64 + lane];
      acc.x = fmaf(w, hh.x, acc.x);
      acc.y = fmaf(w, hh.y, acc.y);
    }
  }
  float inv = 1.f / den;
  return make_float2(fmaxf(acc.x * inv + bv.x, 0.f), fmaxf(acc.y * inv + bv.y, 0.f));
}

// ---- GAT + pairwise max-pool + BN-stats partial; one wave per pooled pair ----
__device__ void dev_gat(SM& sm, const float* __restrict__ h, const float* __restrict__ es,
                        const float* __restrict__ ed, const int* __restrict__ csr_src,
                        const int* __restrict__ rs, const int* __restrict__ rc,
                        const float* __restrict__ bias, float* __restrict__ xout,
                        float* __restrict__ bnsum, int npairs, int workerId, int nWorkers){
  int lane = threadIdx.x & 63, wave = threadIdx.x >> 6;
  const float2* h2 = (const float2*)h;
  float2 bv = ((const float2*)bias)[lane];
  float4 part = make_float4(0.f, 0.f, 0.f, 0.f);
  for (int p = workerId * 16 + wave; p < npairs; p += nWorkers * 16){
    float2 o0 = dev_gat_node(h2, es, ed, csr_src, rs, rc, bv, 2 * p,     lane);
    float2 o1 = dev_gat_node(h2, es, ed, csr_src, rs, rc, bv, 2 * p + 1, lane);
    float2 pl; pl.x = fmaxf(o0.x, o1.x); pl.y = fmaxf(o0.y, o1.y);
    ((float2*)xout)[(size_t)p * 64 + lane] = pl;
    part.x += pl.x; part.y += pl.y; part.z += pl.x * pl.x; part.w += pl.y * pl.y;
  }
  sm.b.bnred[wave * 64 + lane] = part;
  __syncthreads();
  if (wave == 0){
    float4 a = sm.b.bnred[lane];
    #pragma unroll
    for (int w = 1; w < 16; ++w){
      float4 b = sm.b.bnred[w * 64 + lane];
      a.x += b.x; a.y += b.y; a.z += b.z; a.w += b.w;
    }
    atomicAdd(&bnsum[2 * lane],       a.x);
    atomicAdd(&bnsum[2 * lane + 1],   a.y);
    atomicAdd(&bnsum[128 + 2 * lane],     a.z);
    atomicAdd(&bnsum[128 + 2 * lane + 1], a.w);
  }
}

// ---- the persistent mega-kernel: all 3 layers, 6 grid barriers ----
__global__ __launch_bounds__(NTHR)
void mega(const float* __restrict__ x0, const float* __restrict__ W0,
          const float* __restrict__ W1, const float* __restrict__ W2,
          const float* __restrict__ attS, const float* __restrict__ attD,
          const float* __restrict__ bias,
          const int* __restrict__ src0, const int* __restrict__ dst0,
          float* Hbuf, float* Xbuf, float* es, float* ed,
          int* csr1, int* rs1, int* rc1,
          int* csr2, int* rs2, int* rc2,
          int* csr3, int* rs3, int* rc3,
          unsigned char* mask2, unsigned char* mask3,
          unsigned int* bitmap0, unsigned int* bitmap1,
          float* bnsums, unsigned* bar, float* out){
  __shared__ SM sm;
  int blk = blockIdx.x;
  float* bnsum0 = bnsums, *bnsum1 = bnsums + 256, *bnsum2 = bnsums + 512;

  // P1: csr L1 (blocks 0..31, zero own bitmap0 slice inline) || gemm L1 (blocks 32..255)
  if (blk < 32){
    dev_csr(sm, src0, dst0, nullptr, csr1, rs1, rc1, 0, 1024, mask2, bitmap0, 1, 9, blk);
  } else {
    if (blk == 32){
      for (int i = threadIdx.x; i < 768; i += NTHR) bnsums[i] = 0.f;
    }
    dev_gemm<64>(sm, x0, W0, nullptr, 0.f, attS, attD, Hbuf, es, ed, 32768, blk - 32, 224);
  }
  grid_barrier(bar);

  // P2: csr L2 (0..31) || gat L1 + pool + bn0 (32..255)
  if (blk < 32){
    dev_csr(sm, src0, dst0, mask2, csr2, rs2, rc2, 1, 512, mask3, bitmap1, 2, 8, blk);
  } else {
    dev_gat(sm, Hbuf, es, ed, csr1, rs1, rc1, bias, Xbuf, bnsum0, 16384, blk - 32, 224);
  }
  grid_barrier(bar);

  // P3: csr L3 (0..31) || gemm L2 (32..255)
  if (blk < 32){
    dev_csr(sm, src0, dst0, mask3, csr3, rs3, rc3, 2, 256, nullptr, nullptr, 0, 0, blk);
  } else {
    dev_gemm<128>(sm, Xbuf, W1, bnsum0, 1.f / 16384.f, attS + 128, attD + 128,
                  Hbuf, es, ed, 16384, blk - 32, 224);
  }
  grid_barrier(bar);

  // P4: gat L2 + pool + bn1 (all)
  dev_gat(sm, Hbuf, es, ed, csr2, rs2, rc2, bias + 128, Xbuf, bnsum1, 8192, blk, NBLK);
  grid_barrier(bar);

  // P5: gemm L3 (all)
  dev_gemm<128>(sm, Xbuf, W2, bnsum1, 1.f / 8192.f, attS + 256, attD + 256,
                Hbuf, es, ed, 8192, blk, NBLK);
  grid_barrier(bar);

  // P6: gat L3 + pool + bn2 (all)
  dev_gat(sm, Hbuf, es, ed, csr3, rs3, rc3, bias + 256, Xbuf, bnsum2, 4096, blk, NBLK);
  grid_barrier(bar);

  // P7: final BatchNorm apply -> out (4096 rows x 128)
  {
    float2* o2 = (float2*)out;
    const float2* x2 = (const float2*)Xbuf;
    int total = 4096 * 64;
    for (int i = blk * NTHR + threadIdx.x; i < total; i += NBLK * NTHR){
      int c2 = i & 63;
      float mu0 = bnsum2[2 * c2] * (1.f / 4096.f);
      float mu1 = bnsum2[2 * c2 + 1] * (1.f / 4096.f);
      float v0 = bnsum2[128 + 2 * c2] * (1.f / 4096.f) - mu0 * mu0;
      float v1 = bnsum2[128 + 2 * c2 + 1] * (1.f / 4096.f) - mu1 * mu1;
      float2 v = x2[i];
      o2[i] = make_float2((v.x - mu0) * rsqrtf(v0 + EPS_BN),
                          (v.y - mu1) * rsqrtf(v1 + EPS_BN));
    }
  }
}

extern "C" void kernel_launch(void* const* d_in, const int* in_sizes, int n_in,
                              void* d_out, int out_size, void* d_ws, size_t ws_size,
                              hipStream_t stream){
  const float* x0   = (const float*)d_in[0];
  const float* W0   = (const float*)d_in[1];
  const float* W1   = (const float*)d_in[2];
  const float* W2   = (const float*)d_in[3];
  const float* attS = (const float*)d_in[4];
  const float* attD = (const float*)d_in[5];
  const float* bias = (const float*)d_in[6];
  const int*   src0 = (const int*)d_in[7];
  const int*   dst0 = src0 + E_TOTAL;
  float* out = (float*)d_out;

  char* ws = (char*)d_ws;
  float*         Hbuf    = (float*)(ws);                          // 16 MB
  float*         Xbuf    = (float*)(ws + (16u << 20));            //  8 MB
  float*         es      = (float*)(ws + (24u << 20));            // 128 KB
  float*         ed      = (float*)(ws + (24u << 20) + (128u << 10));
  int*           csr1    = (int*)  (ws + (25u << 20));            // 1 MB
  int*           csr2    = (int*)  (ws + (26u << 20));            // 1 MB
  int*           csr3    = (int*)  (ws + (27u << 20));            // 1 MB
  int*           rs1     = (int*)  (ws + (28u << 20));            // 128 KB each
  int*           rc1     = (int*)  (ws + (28u << 20) + 1 * (128u << 10));
  int*           rs2     = (int*)  (ws + (28u << 20) + 2 * (128u << 10));
  int*           rc2     = (int*)  (ws + (28u << 20) + 3 * (128u << 10));
  int*           rs3     = (int*)  (ws + (28u << 20) + 4 * (128u << 10));
  int*           rc3     = (int*)  (ws + (28u << 20) + 5 * (128u << 10));
  unsigned char* mask2   = (unsigned char*)(ws + (29u << 20));           // 256 KB
  unsigned char* mask3   = (unsigned char*)(ws + (29u << 20) + (256u << 10));
  unsigned int*  bitmap0 = (unsigned int*)(ws + (30u << 20));            // 1 MB
  unsigned int*  bitmap1 = (unsigned int*)(ws + (31u << 20));            // 256 KB
  float*         bnsums  = (float*)(ws + (31u << 20) + (256u << 10));    // 768 floats
  unsigned*      bar     = (unsigned*)(ws + (31u << 20) + (512u << 10)); // 1 word

  hipMemsetAsync(bar, 0, sizeof(unsigned), stream);
  hipLaunchKernelGGL(mega, dim3(NBLK), dim3(NTHR), 0, stream,
                     x0, W0, W1, W2, attS, attD, bias, src0, dst0,
                     Hbuf, Xbuf, es, ed,
                     csr1, rs1, rc1, csr2, rs2, rc2, csr3, rs3, rc3,
                     mask2, mask3, bitmap0, bitmap1, bnsums, bar, out);
}

// Round 5
// 368.165 us; speedup vs baseline: 1.2608x; 1.2608x over previous
//
#include <hip/hip_runtime.h>

// Problem constants: B=32 graphs, N=1024 nodes/graph, F=64, D=128, DEG=8
#define E_TOTAL 262144
#define NGRAPH  32
#define EPG     8192
#define EPS_BN  1e-5f
#define NBLK    256
#define NTHR    1024

__device__ __forceinline__ float lrelu(float x){ return x > 0.f ? x : 0.2f * x; }

// LDS union across phases; max member ~49.7 KB (<64 KB static limit, 1+ block/CU).
struct SM {
  union {
    struct { float Ws[64 * 128]; float As_t[64 * 66]; } g;    // 32 KB + 16.5 KB (gemm)
    struct { int cnt[1024]; int pos[1024]; int wsum[16]; } c; // 8.3 KB (csr)
    struct { float4 bnred[16 * 64]; } b;                      // 16 KB (gat bn reduce)
  };
};

// ---- device-scope grid barrier (all NBLK blocks co-resident by construction) ----
// CRITICAL: poll with RELAXED load. An agent-scope ACQUIRE load emits a cache
// invalidate per poll iteration -> L2 invalidation storm (round-4 regression:
// 397us, FETCH_SIZE 130MB). One release fence before arrive, one acquire fence
// after the wait completes.
__device__ __forceinline__ void grid_barrier(unsigned* bar){
  __syncthreads();
  if (threadIdx.x == 0){
    __threadfence();  // release: make this block's stores visible at device scope
    unsigned arr = atomicAdd(bar, 1u);   // device-scope, relaxed
    unsigned target = (arr / NBLK + 1u) * NBLK;
    while (__hip_atomic_load(bar, __ATOMIC_RELAXED, __HIP_MEMORY_SCOPE_AGENT) < target)
      __builtin_amdgcn_s_sleep(4);
    __threadfence();  // acquire: invalidate stale cached lines ONCE
  }
  __syncthreads();
}

// ---- GEMM + attention terms: C = bn(A)@W, es/ed via wave shuffle-reduce ----
// 64-row tiles; 16 waves/block, wave rg owns rows rg*4..rg*4+3; lane = channel pair.
// A tile staged transposed in LDS, stride 66: 2-way write aliasing (free),
// broadcast reads; W chunk in LDS, 4-way read aliasing (1.58x, acceptable).
template<int K>
__device__ void dev_gemm(SM& sm, const float* __restrict__ A, const float* __restrict__ W,
                         const float* __restrict__ bnsums, float invM,
                         const float* __restrict__ a_s, const float* __restrict__ a_d,
                         float* __restrict__ C, float* __restrict__ es, float* __restrict__ ed,
                         int M, int workerId, int nWorkers){
  int tid = threadIdx.x, lane = tid & 63, rg = tid >> 6;
  float mu0 = 0.f, rs0 = 1.f, mu1 = 0.f, rs1 = 1.f;
  if (bnsums){
    mu0 = bnsums[lane] * invM;
    float v0 = bnsums[K + lane] * invM - mu0 * mu0;
    rs0 = rsqrtf(v0 + EPS_BN);
    if (K > 64){
      mu1 = bnsums[lane + 64] * invM;
      float v1 = bnsums[K + lane + 64] * invM - mu1 * mu1;
      rs1 = rsqrtf(v1 + EPS_BN);
    }
  }
  float2 as2 = ((const float2*)a_s)[lane];
  float2 ad2 = ((const float2*)a_d)[lane];
  int ntiles = M >> 6;
  for (int t = workerId; t < ntiles; t += nWorkers){
    int row0 = t << 6;
    float2 acc[4] = {};
    for (int k0 = 0; k0 < K; k0 += 64){
      float mu = k0 ? mu1 : mu0, rs = k0 ? rs1 : rs0;
      __syncthreads();
      for (int i = tid; i < 8192; i += NTHR)
        sm.g.Ws[i] = W[(size_t)(k0 + (i >> 7)) * 128 + (i & 127)];
      #pragma unroll
      for (int it = 0; it < 4; ++it){
        int r = it * 16 + rg;                      // row within tile
        float v = A[(size_t)(row0 + r) * K + k0 + lane];  // 64-lane coalesced
        sm.g.As_t[lane * 66 + r] = (v - mu) * rs;
      }
      __syncthreads();
      #pragma unroll 8
      for (int kk = 0; kk < 64; ++kk){
        float2 w   = *(float2*)&sm.g.Ws[kk * 128 + lane * 2];
        float2 a01 = *(float2*)&sm.g.As_t[kk * 66 + rg * 4];      // broadcast
        float2 a23 = *(float2*)&sm.g.As_t[kk * 66 + rg * 4 + 2];  // broadcast
        acc[0].x = fmaf(a01.x, w.x, acc[0].x); acc[0].y = fmaf(a01.x, w.y, acc[0].y);
        acc[1].x = fmaf(a01.y, w.x, acc[1].x); acc[1].y = fmaf(a01.y, w.y, acc[1].y);
        acc[2].x = fmaf(a23.x, w.x, acc[2].x); acc[2].y = fmaf(a23.x, w.y, acc[2].y);
        acc[3].x = fmaf(a23.y, w.x, acc[3].x); acc[3].y = fmaf(a23.y, w.y, acc[3].y);
      }
    }
    #pragma unroll
    for (int i = 0; i < 4; ++i){
      int r = row0 + rg * 4 + i;
      ((float2*)C)[(size_t)r * 64 + lane] = acc[i];
      float e1 = acc[i].x * as2.x + acc[i].y * as2.y;
      float e2 = acc[i].x * ad2.x + acc[i].y * ad2.y;
      #pragma unroll
      for (int o = 32; o; o >>= 1){ e1 += __shfl_xor(e1, o); e2 += __shfl_xor(e2, o); }
      if (lane == 0){ es[r] = e1; ed[r] = e2; }
    }
  }
}

// ---- per-graph counting sort by dst + inline dedupe-for-next-layer; one block/graph ----
__device__ void dev_csr(SM& sm, const int* __restrict__ src0, const int* __restrict__ dst0,
                        const unsigned char* __restrict__ maskIn,
                        int* __restrict__ csr_src, int* __restrict__ row_start,
                        int* __restrict__ row_cnt, int shift, int Npg,
                        unsigned char* __restrict__ maskOut, unsigned int* __restrict__ bitmap,
                        int shiftN, int log2NpgN, int g){
  int t = threadIdx.x;
  int ebase = g * EPG;
  unsigned int* bmg = nullptr;
  if (bitmap){
    int words = 1 << (2 * log2NpgN - 5);    // per-graph bitmap slice
    bmg = bitmap + (size_t)g * words;
    for (int i = t; i < words; i += NTHR) bmg[i] = 0;
  }
  if (t < Npg) sm.c.cnt[t] = 0;
  __syncthreads();
  unsigned keep = 0;
  #pragma unroll
  for (int k = 0; k < 8; ++k){
    int e = ebase + t + k * NTHR;
    int sv = src0[e], dv = dst0[e];
    bool act = maskIn ? (maskIn[e] != 0) : (sv != dv);
    if (act){
      keep |= (1u << k);
      atomicAdd(&sm.c.cnt[(dv >> shift) & (Npg - 1)], 1);
    }
    if (maskOut){
      unsigned char m2 = 0;
      if (act){
        int s2 = sv >> shiftN, d2 = dv >> shiftN;
        if (s2 != d2){
          int NpgN = 1 << log2NpgN;
          unsigned key = ((unsigned)(s2 & (NpgN - 1)) << log2NpgN) | (unsigned)(d2 & (NpgN - 1));
          unsigned bit = 1u << (key & 31u);
          unsigned old = atomicOr(&bmg[key >> 5], bit);
          m2 = (old & bit) ? 0 : 1;
        }
      }
      maskOut[e] = m2;
    }
  }
  __syncthreads();
  int c = (t < Npg) ? sm.c.cnt[t] : 0;
  int lane = t & 63, w = t >> 6;
  int v = c;
  #pragma unroll
  for (int o = 1; o < 64; o <<= 1){
    int u = __shfl_up(v, o);
    if (lane >= o) v += u;
  }
  if (lane == 63) sm.c.wsum[w] = v;
  __syncthreads();
  if (t == 0){
    int run = 0;
    #pragma unroll
    for (int i = 0; i < 16; ++i){ int x = sm.c.wsum[i]; sm.c.wsum[i] = run; run += x; }
  }
  __syncthreads();
  int excl = v - c + sm.c.wsum[w];
  if (t < Npg){
    sm.c.pos[t] = excl;
    row_start[g * Npg + t] = ebase + excl;
    row_cnt[g * Npg + t]   = c;
  }
  __syncthreads();
  #pragma unroll
  for (int k = 0; k < 8; ++k){
    if (keep & (1u << k)){
      int e = ebase + t + k * NTHR;
      int d = (dst0[e] >> shift) & (Npg - 1);
      int p = atomicAdd(&sm.c.pos[d], 1);
      csr_src[ebase + p] = src0[e] >> shift;
    }
  }
}

// ---- one GAT node (softmax over neighbors + self loop), returns relu(agg+bias) ----
__device__ float2 dev_gat_node(const float2* __restrict__ h2, const float* __restrict__ es,
                               const float* __restrict__ ed, const int* __restrict__ csr_src,
                               const int* __restrict__ row_start, const int* __restrict__ row_cnt,
                               float2 bv, int n, int lane){
  int start = row_start[n];
  int cnt   = row_cnt[n];
  float edn = ed[n];
  float selfl = lrelu(es[n] + edn);
  float m_l = -1e30f, d_l = 0.f;
  for (int c0 = 0; c0 < cnt; c0 += 64){
    int j = c0 + lane;
    if (j < cnt){
      int s = csr_src[start + j];
      float l = lrelu(es[s] + edn);
      float mn = fmaxf(m_l, l);
      d_l = d_l * __expf(m_l - mn) + __expf(l - mn);
      m_l = mn;
    }
  }
  #pragma unroll
  for (int o = 32; o; o >>= 1){
    float m2 = __shfl_xor(m_l, o), d2 = __shfl_xor(d_l, o);
    float mn = fmaxf(m_l, m2);
    d_l = d_l * __expf(m_l - mn) + d2 * __expf(m2 - mn);
    m_l = mn;
  }
  float mf  = fmaxf(m_l, selfl);
  float den = d_l * __expf(m_l - mf) + __expf(selfl - mf);
  float sw  = __expf(selfl - mf);
  float2 hv = h2[(size_t)n * 64 + lane];
  float2 acc; acc.x = sw * hv.x; acc.y = sw * hv.y;
  for (int c0 = 0; c0 < cnt; c0 += 64){
    int j = c0 + lane;
    int s_j = 0; float w_j = 0.f;
    if (j < cnt){
      s_j = csr_src[start + j];
      w_j = __expf(lrelu(es[s_j] + edn) - mf);
    }
    int rem = min(64, cnt - c0);
    int k = 0;
    for (; k + 8 <= rem; k += 8){
      int ss[8]; float ww[8]; float2 hh[8];
      #pragma unroll
      for (int i = 0; i < 8; ++i){ ss[i] = __shfl(s_j, k + i); ww[i] = __shfl(w_j, k + i); }
      #pragma unroll
      for (int i = 0; i < 8; ++i) hh[i] = h2[(size_t)ss[i] * 64 + lane];
      #pragma unroll
      for (int i = 0; i < 8; ++i){
        acc.x = fmaf(ww[i], hh[i].x, acc.x);
        acc.y = fmaf(ww[i], hh[i].y, acc.y);
      }
    }
    for (; k < rem; ++k){
      int s = __shfl(s_j, k); float w = __shfl(w_j, k);
      float2 hh = h2[(size_t)s * 64 + lane];
      acc.x = fmaf(w, hh.x, acc.x);
      acc.y = fmaf(w, hh.y, acc.y);
    }
  }
  float inv = 1.f / den;
  return make_float2(fmaxf(acc.x * inv + bv.x, 0.f), fmaxf(acc.y * inv + bv.y, 0.f));
}

// ---- GAT + pairwise max-pool + BN-stats partial; one wave per pooled pair ----
__device__ void dev_gat(SM& sm, const float* __restrict__ h, const float* __restrict__ es,
                        const float* __restrict__ ed, const int* __restrict__ csr_src,
                        const int* __restrict__ rs, const int* __restrict__ rc,
                        const float* __restrict__ bias, float* __restrict__ xout,
                        float* __restrict__ bnsum, int npairs, int workerId, int nWorkers){
  int lane = threadIdx.x & 63, wave = threadIdx.x >> 6;
  const float2* h2 = (const float2*)h;
  float2 bv = ((const float2*)bias)[lane];
  float4 part = make_float4(0.f, 0.f, 0.f, 0.f);
  for (int p = workerId * 16 + wave; p < npairs; p += nWorkers * 16){
    float2 o0 = dev_gat_node(h2, es, ed, csr_src, rs, rc, bv, 2 * p,     lane);
    float2 o1 = dev_gat_node(h2, es, ed, csr_src, rs, rc, bv, 2 * p + 1, lane);
    float2 pl; pl.x = fmaxf(o0.x, o1.x); pl.y = fmaxf(o0.y, o1.y);
    ((float2*)xout)[(size_t)p * 64 + lane] = pl;
    part.x += pl.x; part.y += pl.y; part.z += pl.x * pl.x; part.w += pl.y * pl.y;
  }
  sm.b.bnred[wave * 64 + lane] = part;
  __syncthreads();
  if (wave == 0){
    float4 a = sm.b.bnred[lane];
    #pragma unroll
    for (int w = 1; w < 16; ++w){
      float4 b = sm.b.bnred[w * 64 + lane];
      a.x += b.x; a.y += b.y; a.z += b.z; a.w += b.w;
    }
    atomicAdd(&bnsum[2 * lane],           a.x);
    atomicAdd(&bnsum[2 * lane + 1],       a.y);
    atomicAdd(&bnsum[128 + 2 * lane],     a.z);
    atomicAdd(&bnsum[128 + 2 * lane + 1], a.w);
  }
}

// ---- persistent mega-kernel: all 3 layers, 6 grid barriers ----
__global__ __launch_bounds__(NTHR)
void mega(const float* __restrict__ x0, const float* __restrict__ W0,
          const float* __restrict__ W1, const float* __restrict__ W2,
          const float* __restrict__ attS, const float* __restrict__ attD,
          const float* __restrict__ bias,
          const int* __restrict__ src0, const int* __restrict__ dst0,
          float* Hbuf, float* Xbuf, float* es, float* ed,
          int* csr1, int* rs1, int* rc1,
          int* csr2, int* rs2, int* rc2,
          int* csr3, int* rs3, int* rc3,
          unsigned char* mask2, unsigned char* mask3,
          unsigned int* bitmap0, unsigned int* bitmap1,
          float* bnsums, unsigned* bar, float* out){
  __shared__ SM sm;
  int blk = blockIdx.x;
  float* bnsum0 = bnsums, *bnsum1 = bnsums + 256, *bnsum2 = bnsums + 512;

  // P1: csr L1 (blocks 0..31) || gemm L1 (blocks 32..255); block 32 zeroes bnsums
  if (blk < 32){
    dev_csr(sm, src0, dst0, nullptr, csr1, rs1, rc1, 0, 1024, mask2, bitmap0, 1, 9, blk);
  } else {
    if (blk == 32){
      for (int i = threadIdx.x; i < 768; i += NTHR) bnsums[i] = 0.f;
    }
    dev_gemm<64>(sm, x0, W0, nullptr, 0.f, attS, attD, Hbuf, es, ed, 32768, blk - 32, 224);
  }
  grid_barrier(bar);

  // P2: csr L2 (0..31) || gat L1 + pool + bn0 (32..255)
  if (blk < 32){
    dev_csr(sm, src0, dst0, mask2, csr2, rs2, rc2, 1, 512, mask3, bitmap1, 2, 8, blk);
  } else {
    dev_gat(sm, Hbuf, es, ed, csr1, rs1, rc1, bias, Xbuf, bnsum0, 16384, blk - 32, 224);
  }
  grid_barrier(bar);

  // P3: csr L3 (0..31) || gemm L2 (32..255)
  if (blk < 32){
    dev_csr(sm, src0, dst0, mask3, csr3, rs3, rc3, 2, 256, nullptr, nullptr, 0, 0, blk);
  } else {
    dev_gemm<128>(sm, Xbuf, W1, bnsum0, 1.f / 16384.f, attS + 128, attD + 128,
                  Hbuf, es, ed, 16384, blk - 32, 224);
  }
  grid_barrier(bar);

  // P4: gat L2 + pool + bn1 (all)
  dev_gat(sm, Hbuf, es, ed, csr2, rs2, rc2, bias + 128, Xbuf, bnsum1, 8192, blk, NBLK);
  grid_barrier(bar);

  // P5: gemm L3 (all)
  dev_gemm<128>(sm, Xbuf, W2, bnsum1, 1.f / 8192.f, attS + 256, attD + 256,
                Hbuf, es, ed, 8192, blk, NBLK);
  grid_barrier(bar);

  // P6: gat L3 + pool + bn2 (all)
  dev_gat(sm, Hbuf, es, ed, csr3, rs3, rc3, bias + 256, Xbuf, bnsum2, 4096, blk, NBLK);
  grid_barrier(bar);

  // P7: final BatchNorm apply -> out (4096 rows x 128)
  {
    float2* o2 = (float2*)out;
    const float2* x2 = (const float2*)Xbuf;
    int total = 4096 * 64;
    for (int i = blk * NTHR + threadIdx.x; i < total; i += NBLK * NTHR){
      int c2 = i & 63;
      float mu0 = bnsum2[2 * c2] * (1.f / 4096.f);
      float mu1 = bnsum2[2 * c2 + 1] * (1.f / 4096.f);
      float v0 = bnsum2[128 + 2 * c2] * (1.f / 4096.f) - mu0 * mu0;
      float v1 = bnsum2[128 + 2 * c2 + 1] * (1.f / 4096.f) - mu1 * mu1;
      float2 v = x2[i];
      o2[i] = make_float2((v.x - mu0) * rsqrtf(v0 + EPS_BN),
                          (v.y - mu1) * rsqrtf(v1 + EPS_BN));
    }
  }
}

extern "C" void kernel_launch(void* const* d_in, const int* in_sizes, int n_in,
                              void* d_out, int out_size, void* d_ws, size_t ws_size,
                              hipStream_t stream){
  const float* x0   = (const float*)d_in[0];
  const float* W0   = (const float*)d_in[1];
  const float* W1   = (const float*)d_in[2];
  const float* W2   = (const float*)d_in[3];
  const float* attS = (const float*)d_in[4];
  const float* attD = (const float*)d_in[5];
  const float* bias = (const float*)d_in[6];
  const int*   src0 = (const int*)d_in[7];
  const int*   dst0 = src0 + E_TOTAL;
  float* out = (float*)d_out;

  char* ws = (char*)d_ws;
  float*         Hbuf    = (float*)(ws);                          // 16 MB
  float*         Xbuf    = (float*)(ws + (16u << 20));            //  8 MB
  float*         es      = (float*)(ws + (24u << 20));            // 128 KB
  float*         ed      = (float*)(ws + (24u << 20) + (128u << 10));
  int*           csr1    = (int*)  (ws + (25u << 20));            // 1 MB
  int*           csr2    = (int*)  (ws + (26u << 20));            // 1 MB
  int*           csr3    = (int*)  (ws + (27u << 20));            // 1 MB
  int*           rs1     = (int*)  (ws + (28u << 20));            // 128 KB each
  int*           rc1     = (int*)  (ws + (28u << 20) + 1 * (128u << 10));
  int*           rs2     = (int*)  (ws + (28u << 20) + 2 * (128u << 10));
  int*           rc2     = (int*)  (ws + (28u << 20) + 3 * (128u << 10));
  int*           rs3     = (int*)  (ws + (28u << 20) + 4 * (128u << 10));
  int*           rc3     = (int*)  (ws + (28u << 20) + 5 * (128u << 10));
  unsigned char* mask2   = (unsigned char*)(ws + (29u << 20));           // 256 KB
  unsigned char* mask3   = (unsigned char*)(ws + (29u << 20) + (256u << 10));
  unsigned int*  bitmap0 = (unsigned int*)(ws + (30u << 20));            // 1 MB
  unsigned int*  bitmap1 = (unsigned int*)(ws + (31u << 20));            // 256 KB
  float*         bnsums  = (float*)(ws + (31u << 20) + (256u << 10));    // 768 floats
  unsigned*      bar     = (unsigned*)(ws + (31u << 20) + (512u << 10)); // 1 word

  hipMemsetAsync(bar, 0, sizeof(unsigned), stream);
  hipLaunchKernelGGL(mega, dim3(NBLK), dim3(NTHR), 0, stream,
                     x0, W0, W1, W2, attS, attD, bias, src0, dst0,
                     Hbuf, Xbuf, es, ed,
                     csr1, rs1, rc1, csr2, rs2, rc2, csr3, rs3, rc3,
                     mask2, mask3, bitmap0, bitmap1, bnsums, bar, out);
}

// Round 6
// 310.406 us; speedup vs baseline: 1.4954x; 1.1861x over previous
//
#include <hip/hip_runtime.h>

// Problem constants: B=32 graphs, N=1024 nodes/graph, F=64, D=128, DEG=8
#define E_TOTAL 262144
#define NGRAPH  32
#define EPG     8192
#define EPS_BN  1e-5f
#define NBLK    256
#define NTHR    1024

__device__ __forceinline__ float lrelu(float x){ return x > 0.f ? x : 0.2f * x; }

// LDS union across phases; max member ~49.7 KB (<64 KB static limit, 1 block/CU min).
struct SM {
  union {
    struct { float Ws[64 * 128]; float As_t[64 * 66]; } g;    // 32 KB + 16.5 KB (gemm)
    struct { int cnt[1024]; int pos[1024]; int wsum[16]; } c; // 8.3 KB (csr)
    struct { float4 bnred[16 * 64]; } b;                      // 16 KB (gat bn reduce)
  };
};

// ---- two-level epoch grid barrier ----
// Round-4 lesson: agent-scope ACQUIRE poll => cache-inv storm (397us).
// Round-5 lesson: single-counter atomicAdd barrier => 256 same-line device-scope
// RMWs serialize (~30us/barrier) + uncached poll traffic (FETCH 128MB).
// This version: arrive = plain relaxed store to a per-block line (no RMW, no
// contention); block 0 wave 0 scans flags; one release word; waiters poll it
// with s_sleep backoff. One release fence before arrive, one acquire fence after.
__device__ __forceinline__ void grid_barrier(unsigned* flags, unsigned* rel, unsigned epoch){
  __syncthreads();
  int tid = threadIdx.x;
  if (tid == 0){
    __threadfence();   // release: this block's stores visible device-wide
    __hip_atomic_store(&flags[blockIdx.x * 16], epoch,
                       __ATOMIC_RELAXED, __HIP_MEMORY_SCOPE_AGENT);
  }
  if (blockIdx.x == 0){
    if (tid < 64){
      for (int i = tid; i < NBLK; i += 64){
        while (__hip_atomic_load(&flags[i * 16], __ATOMIC_RELAXED,
                                 __HIP_MEMORY_SCOPE_AGENT) < epoch)
          __builtin_amdgcn_s_sleep(1);
      }
    }
    __syncthreads();   // wave 0 finished scanning
    if (tid == 0)
      __hip_atomic_store(rel, epoch, __ATOMIC_RELAXED, __HIP_MEMORY_SCOPE_AGENT);
  }
  if (tid == 0){
    while (__hip_atomic_load(rel, __ATOMIC_RELAXED, __HIP_MEMORY_SCOPE_AGENT) < epoch)
      __builtin_amdgcn_s_sleep(8);
    __threadfence();   // acquire: invalidate stale cached lines ONCE
  }
  __syncthreads();
}

// ---- GEMM + attention terms: C = bn(A)@W, es/ed via wave shuffle-reduce ----
// 64-row tiles; 16 waves/block, wave rg owns rows rg*4..rg*4+3; lane = channel pair.
template<int K>
__device__ void dev_gemm(SM& sm, const float* __restrict__ A, const float* __restrict__ W,
                         const float* __restrict__ bnsums, float invM,
                         const float* __restrict__ a_s, const float* __restrict__ a_d,
                         float* __restrict__ C, float* __restrict__ es, float* __restrict__ ed,
                         int M, int workerId, int nWorkers){
  int tid = threadIdx.x, lane = tid & 63, rg = tid >> 6;
  float mu0 = 0.f, rs0 = 1.f, mu1 = 0.f, rs1 = 1.f;
  if (bnsums){
    mu0 = bnsums[lane] * invM;
    float v0 = bnsums[K + lane] * invM - mu0 * mu0;
    rs0 = rsqrtf(v0 + EPS_BN);
    if (K > 64){
      mu1 = bnsums[lane + 64] * invM;
      float v1 = bnsums[K + lane + 64] * invM - mu1 * mu1;
      rs1 = rsqrtf(v1 + EPS_BN);
    }
  }
  float2 as2 = ((const float2*)a_s)[lane];
  float2 ad2 = ((const float2*)a_d)[lane];
  int ntiles = M >> 6;
  for (int t = workerId; t < ntiles; t += nWorkers){
    int row0 = t << 6;
    float2 acc[4] = {};
    for (int k0 = 0; k0 < K; k0 += 64){
      float mu = k0 ? mu1 : mu0, rs = k0 ? rs1 : rs0;
      __syncthreads();
      for (int i = tid; i < 8192; i += NTHR)
        sm.g.Ws[i] = W[(size_t)(k0 + (i >> 7)) * 128 + (i & 127)];
      #pragma unroll
      for (int it = 0; it < 4; ++it){
        int r = it * 16 + rg;                             // row within tile
        float v = A[(size_t)(row0 + r) * K + k0 + lane];  // 64-lane coalesced
        sm.g.As_t[lane * 66 + r] = (v - mu) * rs;
      }
      __syncthreads();
      #pragma unroll 8
      for (int kk = 0; kk < 64; ++kk){
        float2 w   = *(float2*)&sm.g.Ws[kk * 128 + lane * 2];
        float2 a01 = *(float2*)&sm.g.As_t[kk * 66 + rg * 4];      // broadcast
        float2 a23 = *(float2*)&sm.g.As_t[kk * 66 + rg * 4 + 2];  // broadcast
        acc[0].x = fmaf(a01.x, w.x, acc[0].x); acc[0].y = fmaf(a01.x, w.y, acc[0].y);
        acc[1].x = fmaf(a01.y, w.x, acc[1].x); acc[1].y = fmaf(a01.y, w.y, acc[1].y);
        acc[2].x = fmaf(a23.x, w.x, acc[2].x); acc[2].y = fmaf(a23.x, w.y, acc[2].y);
        acc[3].x = fmaf(a23.y, w.x, acc[3].x); acc[3].y = fmaf(a23.y, w.y, acc[3].y);
      }
    }
    #pragma unroll
    for (int i = 0; i < 4; ++i){
      int r = row0 + rg * 4 + i;
      ((float2*)C)[(size_t)r * 64 + lane] = acc[i];
      float e1 = acc[i].x * as2.x + acc[i].y * as2.y;
      float e2 = acc[i].x * ad2.x + acc[i].y * ad2.y;
      #pragma unroll
      for (int o = 32; o; o >>= 1){ e1 += __shfl_xor(e1, o); e2 += __shfl_xor(e2, o); }
      if (lane == 0){ es[r] = e1; ed[r] = e2; }
    }
  }
}

// ---- per-graph counting sort by dst + inline dedupe-for-next-layer; one block/graph ----
__device__ void dev_csr(SM& sm, const int* __restrict__ src0, const int* __restrict__ dst0,
                        const unsigned char* __restrict__ maskIn,
                        int* __restrict__ csr_src, int* __restrict__ row_start,
                        int* __restrict__ row_cnt, int shift, int Npg,
                        unsigned char* __restrict__ maskOut, unsigned int* __restrict__ bitmap,
                        int shiftN, int log2NpgN, int g){
  int t = threadIdx.x;
  int ebase = g * EPG;
  unsigned int* bmg = nullptr;
  if (bitmap){
    int words = 1 << (2 * log2NpgN - 5);    // per-graph bitmap slice
    bmg = bitmap + (size_t)g * words;
    for (int i = t; i < words; i += NTHR) bmg[i] = 0;
  }
  if (t < Npg) sm.c.cnt[t] = 0;
  __syncthreads();
  unsigned keep = 0;
  #pragma unroll
  for (int k = 0; k < 8; ++k){
    int e = ebase + t + k * NTHR;
    int sv = src0[e], dv = dst0[e];
    bool act = maskIn ? (maskIn[e] != 0) : (sv != dv);
    if (act){
      keep |= (1u << k);
      atomicAdd(&sm.c.cnt[(dv >> shift) & (Npg - 1)], 1);
    }
    if (maskOut){
      unsigned char m2 = 0;
      if (act){
        int s2 = sv >> shiftN, d2 = dv >> shiftN;
        if (s2 != d2){
          int NpgN = 1 << log2NpgN;
          unsigned key = ((unsigned)(s2 & (NpgN - 1)) << log2NpgN) | (unsigned)(d2 & (NpgN - 1));
          unsigned bit = 1u << (key & 31u);
          unsigned old = atomicOr(&bmg[key >> 5], bit);
          m2 = (old & bit) ? 0 : 1;
        }
      }
      maskOut[e] = m2;
    }
  }
  __syncthreads();
  int c = (t < Npg) ? sm.c.cnt[t] : 0;
  int lane = t & 63, w = t >> 6;
  int v = c;
  #pragma unroll
  for (int o = 1; o < 64; o <<= 1){
    int u = __shfl_up(v, o);
    if (lane >= o) v += u;
  }
  if (lane == 63) sm.c.wsum[w] = v;
  __syncthreads();
  if (t == 0){
    int run = 0;
    #pragma unroll
    for (int i = 0; i < 16; ++i){ int x = sm.c.wsum[i]; sm.c.wsum[i] = run; run += x; }
  }
  __syncthreads();
  int excl = v - c + sm.c.wsum[w];
  if (t < Npg){
    sm.c.pos[t] = excl;
    row_start[g * Npg + t] = ebase + excl;
    row_cnt[g * Npg + t]   = c;
  }
  __syncthreads();
  #pragma unroll
  for (int k = 0; k < 8; ++k){
    if (keep & (1u << k)){
      int e = ebase + t + k * NTHR;
      int d = (dst0[e] >> shift) & (Npg - 1);
      int p = atomicAdd(&sm.c.pos[d], 1);
      csr_src[ebase + p] = src0[e] >> shift;
    }
  }
}

// ---- one GAT node (softmax over neighbors + self loop), returns relu(agg+bias) ----
__device__ float2 dev_gat_node(const float2* __restrict__ h2, const float* __restrict__ es,
                               const float* __restrict__ ed, const int* __restrict__ csr_src,
                               const int* __restrict__ row_start, const int* __restrict__ row_cnt,
                               float2 bv, int n, int lane){
  int start = row_start[n];
  int cnt   = row_cnt[n];
  float edn = ed[n];
  float selfl = lrelu(es[n] + edn);
  float m_l = -1e30f, d_l = 0.f;
  for (int c0 = 0; c0 < cnt; c0 += 64){
    int j = c0 + lane;
    if (j < cnt){
      int s = csr_src[start + j];
      float l = lrelu(es[s] + edn);
      float mn = fmaxf(m_l, l);
      d_l = d_l * __expf(m_l - mn) + __expf(l - mn);
      m_l = mn;
    }
  }
  #pragma unroll
  for (int o = 32; o; o >>= 1){
    float m2 = __shfl_xor(m_l, o), d2 = __shfl_xor(d_l, o);
    float mn = fmaxf(m_l, m2);
    d_l = d_l * __expf(m_l - mn) + d2 * __expf(m2 - mn);
    m_l = mn;
  }
  float mf  = fmaxf(m_l, selfl);
  float den = d_l * __expf(m_l - mf) + __expf(selfl - mf);
  float sw  = __expf(selfl - mf);
  float2 hv = h2[(size_t)n * 64 + lane];
  float2 acc; acc.x = sw * hv.x; acc.y = sw * hv.y;
  for (int c0 = 0; c0 < cnt; c0 += 64){
    int j = c0 + lane;
    int s_j = 0; float w_j = 0.f;
    if (j < cnt){
      s_j = csr_src[start + j];
      w_j = __expf(lrelu(es[s_j] + edn) - mf);
    }
    int rem = min(64, cnt - c0);
    int k = 0;
    for (; k + 8 <= rem; k += 8){
      int ss[8]; float ww[8]; float2 hh[8];
      #pragma unroll
      for (int i = 0; i < 8; ++i){ ss[i] = __shfl(s_j, k + i); ww[i] = __shfl(w_j, k + i); }
      #pragma unroll
      for (int i = 0; i < 8; ++i) hh[i] = h2[(size_t)ss[i] * 64 + lane];
      #pragma unroll
      for (int i = 0; i < 8; ++i){
        acc.x = fmaf(ww[i], hh[i].x, acc.x);
        acc.y = fmaf(ww[i], hh[i].y, acc.y);
      }
    }
    for (; k < rem; ++k){
      int s = __shfl(s_j, k); float w = __shfl(w_j, k);
      float2 hh = h2[(size_t)s * 64 + lane];
      acc.x = fmaf(w, hh.x, acc.x);
      acc.y = fmaf(w, hh.y, acc.y);
    }
  }
  float inv = 1.f / den;
  return make_float2(fmaxf(acc.x * inv + bv.x, 0.f), fmaxf(acc.y * inv + bv.y, 0.f));
}

// ---- GAT + pairwise max-pool + BN-stats partial; one wave per pooled pair ----
__device__ void dev_gat(SM& sm, const float* __restrict__ h, const float* __restrict__ es,
                        const float* __restrict__ ed, const int* __restrict__ csr_src,
                        const int* __restrict__ rs, const int* __restrict__ rc,
                        const float* __restrict__ bias, float* __restrict__ xout,
                        float* __restrict__ bnsum, int npairs, int workerId, int nWorkers){
  int lane = threadIdx.x & 63, wave = threadIdx.x >> 6;
  const float2* h2 = (const float2*)h;
  float2 bv = ((const float2*)bias)[lane];
  float4 part = make_float4(0.f, 0.f, 0.f, 0.f);
  for (int p = workerId * 16 + wave; p < npairs; p += nWorkers * 16){
    float2 o0 = dev_gat_node(h2, es, ed, csr_src, rs, rc, bv, 2 * p,     lane);
    float2 o1 = dev_gat_node(h2, es, ed, csr_src, rs, rc, bv, 2 * p + 1, lane);
    float2 pl; pl.x = fmaxf(o0.x, o1.x); pl.y = fmaxf(o0.y, o1.y);
    ((float2*)xout)[(size_t)p * 64 + lane] = pl;
    part.x += pl.x; part.y += pl.y; part.z += pl.x * pl.x; part.w += pl.y * pl.y;
  }
  sm.b.bnred[wave * 64 + lane] = part;
  __syncthreads();
  if (wave == 0){
    float4 a = sm.b.bnred[lane];
    #pragma unroll
    for (int w = 1; w < 16; ++w){
      float4 b = sm.b.bnred[w * 64 + lane];
      a.x += b.x; a.y += b.y; a.z += b.z; a.w += b.w;
    }
    atomicAdd(&bnsum[2 * lane],           a.x);
    atomicAdd(&bnsum[2 * lane + 1],       a.y);
    atomicAdd(&bnsum[128 + 2 * lane],     a.z);
    atomicAdd(&bnsum[128 + 2 * lane + 1], a.w);
  }
}

// ---- persistent mega-kernel: all 3 layers, 6 grid barriers ----
__global__ __launch_bounds__(NTHR)
void mega(const float* __restrict__ x0, const float* __restrict__ W0,
          const float* __restrict__ W1, const float* __restrict__ W2,
          const float* __restrict__ attS, const float* __restrict__ attD,
          const float* __restrict__ bias,
          const int* __restrict__ src0, const int* __restrict__ dst0,
          float* Hbuf, float* Xbuf, float* es, float* ed,
          int* csr1, int* rs1, int* rc1,
          int* csr2, int* rs2, int* rc2,
          int* csr3, int* rs3, int* rc3,
          unsigned char* mask2, unsigned char* mask3,
          unsigned int* bitmap0, unsigned int* bitmap1,
          float* bnsums, unsigned* flags, unsigned* rel, float* out){
  __shared__ SM sm;
  int blk = blockIdx.x;
  float* bnsum0 = bnsums, *bnsum1 = bnsums + 256, *bnsum2 = bnsums + 512;

  // P1: csr L1 (blocks 0..31) || gemm L1 (blocks 32..255); block 32 zeroes bnsums
  if (blk < 32){
    dev_csr(sm, src0, dst0, nullptr, csr1, rs1, rc1, 0, 1024, mask2, bitmap0, 1, 9, blk);
  } else {
    if (blk == 32){
      for (int i = threadIdx.x; i < 768; i += NTHR) bnsums[i] = 0.f;
    }
    dev_gemm<64>(sm, x0, W0, nullptr, 0.f, attS, attD, Hbuf, es, ed, 32768, blk - 32, 224);
  }
  grid_barrier(flags, rel, 1);

  // P2: csr L2 (0..31) || gat L1 + pool + bn0 (32..255)
  if (blk < 32){
    dev_csr(sm, src0, dst0, mask2, csr2, rs2, rc2, 1, 512, mask3, bitmap1, 2, 8, blk);
  } else {
    dev_gat(sm, Hbuf, es, ed, csr1, rs1, rc1, bias, Xbuf, bnsum0, 16384, blk - 32, 224);
  }
  grid_barrier(flags, rel, 2);

  // P3: csr L3 (0..31) || gemm L2 (32..255)
  if (blk < 32){
    dev_csr(sm, src0, dst0, mask3, csr3, rs3, rc3, 2, 256, nullptr, nullptr, 0, 0, blk);
  } else {
    dev_gemm<128>(sm, Xbuf, W1, bnsum0, 1.f / 16384.f, attS + 128, attD + 128,
                  Hbuf, es, ed, 16384, blk - 32, 224);
  }
  grid_barrier(flags, rel, 3);

  // P4: gat L2 + pool + bn1 (all)
  dev_gat(sm, Hbuf, es, ed, csr2, rs2, rc2, bias + 128, Xbuf, bnsum1, 8192, blk, NBLK);
  grid_barrier(flags, rel, 4);

  // P5: gemm L3 (all)
  dev_gemm<128>(sm, Xbuf, W2, bnsum1, 1.f / 8192.f, attS + 256, attD + 256,
                Hbuf, es, ed, 8192, blk, NBLK);
  grid_barrier(flags, rel, 5);

  // P6: gat L3 + pool + bn2 (all)
  dev_gat(sm, Hbuf, es, ed, csr3, rs3, rc3, bias + 256, Xbuf, bnsum2, 4096, blk, NBLK);
  grid_barrier(flags, rel, 6);

  // P7: final BatchNorm apply -> out (4096 rows x 128)
  {
    float2* o2 = (float2*)out;
    const float2* x2 = (const float2*)Xbuf;
    int total = 4096 * 64;
    for (int i = blk * NTHR + threadIdx.x; i < total; i += NBLK * NTHR){
      int c2 = i & 63;
      float mu0 = bnsum2[2 * c2] * (1.f / 4096.f);
      float mu1 = bnsum2[2 * c2 + 1] * (1.f / 4096.f);
      float v0 = bnsum2[128 + 2 * c2] * (1.f / 4096.f) - mu0 * mu0;
      float v1 = bnsum2[128 + 2 * c2 + 1] * (1.f / 4096.f) - mu1 * mu1;
      float2 v = x2[i];
      o2[i] = make_float2((v.x - mu0) * rsqrtf(v0 + EPS_BN),
                          (v.y - mu1) * rsqrtf(v1 + EPS_BN));
    }
  }
}

extern "C" void kernel_launch(void* const* d_in, const int* in_sizes, int n_in,
                              void* d_out, int out_size, void* d_ws, size_t ws_size,
                              hipStream_t stream){
  const float* x0   = (const float*)d_in[0];
  const float* W0   = (const float*)d_in[1];
  const float* W1   = (const float*)d_in[2];
  const float* W2   = (const float*)d_in[3];
  const float* attS = (const float*)d_in[4];
  const float* attD = (const float*)d_in[5];
  const float* bias = (const float*)d_in[6];
  const int*   src0 = (const int*)d_in[7];
  const int*   dst0 = src0 + E_TOTAL;
  float* out = (float*)d_out;

  char* ws = (char*)d_ws;
  float*         Hbuf    = (float*)(ws);                          // 16 MB
  float*         Xbuf    = (float*)(ws + (16u << 20));            //  8 MB
  float*         es      = (float*)(ws + (24u << 20));            // 128 KB
  float*         ed      = (float*)(ws + (24u << 20) + (128u << 10));
  int*           csr1    = (int*)  (ws + (25u << 20));            // 1 MB
  int*           csr2    = (int*)  (ws + (26u << 20));            // 1 MB
  int*           csr3    = (int*)  (ws + (27u << 20));            // 1 MB
  int*           rs1     = (int*)  (ws + (28u << 20));            // 128 KB each
  int*           rc1     = (int*)  (ws + (28u << 20) + 1 * (128u << 10));
  int*           rs2     = (int*)  (ws + (28u << 20) + 2 * (128u << 10));
  int*           rc2     = (int*)  (ws + (28u << 20) + 3 * (128u << 10));
  int*           rs3     = (int*)  (ws + (28u << 20) + 4 * (128u << 10));
  int*           rc3     = (int*)  (ws + (28u << 20) + 5 * (128u << 10));
  unsigned char* mask2   = (unsigned char*)(ws + (29u << 20));           // 256 KB
  unsigned char* mask3   = (unsigned char*)(ws + (29u << 20) + (256u << 10));
  unsigned int*  bitmap0 = (unsigned int*)(ws + (30u << 20));            // 1 MB
  unsigned int*  bitmap1 = (unsigned int*)(ws + (31u << 20));            // 256 KB
  // barrier flags (256 x 64B) + release word + bnsums, contiguous for one memset
  unsigned*      flags   = (unsigned*)(ws + (31u << 20) + (256u << 10)); // 16 KB
  unsigned*      rel     = (unsigned*)(ws + (31u << 20) + (272u << 10)); // 64 B
  float*         bnsums  = (float*)  (ws + (31u << 20) + (273u << 10)); // 768 floats

  hipMemsetAsync(flags, 0, (16u << 10) + 64, stream);   // flags + rel (bnsums zeroed in-kernel)
  hipLaunchKernelGGL(mega, dim3(NBLK), dim3(NTHR), 0, stream,
                     x0, W0, W1, W2, attS, attD, bias, src0, dst0,
                     Hbuf, Xbuf, es, ed,
                     csr1, rs1, rc1, csr2, rs2, rc2, csr3, rs3, rc3,
                     mask2, mask3, bitmap0, bitmap1, bnsums, flags, rel, out);
}

// Round 7
// 281.115 us; speedup vs baseline: 1.6512x; 1.1042x over previous
//
#include <hip/hip_runtime.h>

// Problem constants: B=32 graphs, N=1024 nodes/graph, F=64, D=128, DEG=8
#define E_TOTAL 262144
#define NGRAPH  32
#define EPG     8192
#define EPS_BN  1e-5f
#define NBLK    256
#define NTHR    1024
#define GPX     4     // graphs per XCD (32 graphs / 8 XCDs)

__device__ __forceinline__ float lrelu(float x){ return x > 0.f ? x : 0.2f * x; }

// LDS union across phases; max member ~49.7 KB.
struct SM {
  union {
    struct { float Ws[64 * 128]; float As_t[64 * 66]; } g;    // gemm
    struct { int cnt[1024]; int pos[1024]; int wsum[16]; } c; // csr
    struct { float4 bnred[16 * 64]; } b;                      // gat bn reduce
  };
};

// ---- two-level epoch grid barrier (r4: no acquire-per-poll; r5: no shared-counter RMW) ----
__device__ __forceinline__ void grid_barrier(unsigned* flags, unsigned* rel, unsigned epoch){
  __syncthreads();
  int tid = threadIdx.x;
  if (tid == 0){
    __threadfence();   // release
    __hip_atomic_store(&flags[blockIdx.x * 16], epoch,
                       __ATOMIC_RELAXED, __HIP_MEMORY_SCOPE_AGENT);
  }
  if (blockIdx.x == 0){
    if (tid < 64){
      for (int i = tid; i < NBLK; i += 64){
        while (__hip_atomic_load(&flags[i * 16], __ATOMIC_RELAXED,
                                 __HIP_MEMORY_SCOPE_AGENT) < epoch)
          __builtin_amdgcn_s_sleep(1);
      }
    }
    __syncthreads();
    if (tid == 0)
      __hip_atomic_store(rel, epoch, __ATOMIC_RELAXED, __HIP_MEMORY_SCOPE_AGENT);
  }
  if (tid == 0){
    while (__hip_atomic_load(rel, __ATOMIC_RELAXED, __HIP_MEMORY_SCOPE_AGENT) < epoch)
      __builtin_amdgcn_s_sleep(8);
    __threadfence();   // acquire (once)
  }
  __syncthreads();
}

// ---- GEMM + attention terms, XCD-pinned: tiles of graphs owned by this XCD ----
// bnp: base of per-XCD bn partial slices for the INPUT layer (8 x 256 floats), or null.
template<int K>
__device__ void dev_gemm(SM& sm, const float* __restrict__ A, const float* __restrict__ W,
                         const float* __restrict__ bnp, float invM,
                         const float* __restrict__ a_s, const float* __restrict__ a_d,
                         float* __restrict__ C, float* __restrict__ es, float* __restrict__ ed,
                         int tpg, int x, int wl, int nw){
  int tid = threadIdx.x, lane = tid & 63, rg = tid >> 6;
  float mu0 = 0.f, rs0 = 1.f, mu1 = 0.f, rs1 = 1.f;
  if (bnp){
    float s0 = 0.f, q0 = 0.f, s1 = 0.f, q1 = 0.f;
    #pragma unroll
    for (int xx = 0; xx < 8; ++xx){
      const float* b = bnp + xx * 256;
      s0 += b[lane];      q0 += b[128 + lane];
      s1 += b[64 + lane]; q1 += b[192 + lane];
    }
    mu0 = s0 * invM; rs0 = rsqrtf(q0 * invM - mu0 * mu0 + EPS_BN);
    mu1 = s1 * invM; rs1 = rsqrtf(q1 * invM - mu1 * mu1 + EPS_BN);
  }
  float2 as2 = ((const float2*)a_s)[lane];
  float2 ad2 = ((const float2*)a_d)[lane];
  int ltiles = GPX * tpg;
  for (int lt = wl; lt < ltiles; lt += nw){
    int g = x + 8 * (lt / tpg);
    int row0 = (g * tpg + (lt % tpg)) << 6;
    float2 acc[4] = {};
    for (int k0 = 0; k0 < K; k0 += 64){
      float mu = k0 ? mu1 : mu0, rs = k0 ? rs1 : rs0;
      __syncthreads();
      for (int i = tid; i < 8192; i += NTHR)
        sm.g.Ws[i] = W[(size_t)(k0 + (i >> 7)) * 128 + (i & 127)];
      #pragma unroll
      for (int it = 0; it < 4; ++it){
        int r = it * 16 + rg;
        float v = A[(size_t)(row0 + r) * K + k0 + lane];  // coalesced
        sm.g.As_t[lane * 66 + r] = (v - mu) * rs;
      }
      __syncthreads();
      #pragma unroll 8
      for (int kk = 0; kk < 64; ++kk){
        float2 w   = *(float2*)&sm.g.Ws[kk * 128 + lane * 2];
        float2 a01 = *(float2*)&sm.g.As_t[kk * 66 + rg * 4];
        float2 a23 = *(float2*)&sm.g.As_t[kk * 66 + rg * 4 + 2];
        acc[0].x = fmaf(a01.x, w.x, acc[0].x); acc[0].y = fmaf(a01.x, w.y, acc[0].y);
        acc[1].x = fmaf(a01.y, w.x, acc[1].x); acc[1].y = fmaf(a01.y, w.y, acc[1].y);
        acc[2].x = fmaf(a23.x, w.x, acc[2].x); acc[2].y = fmaf(a23.x, w.y, acc[2].y);
        acc[3].x = fmaf(a23.y, w.x, acc[3].x); acc[3].y = fmaf(a23.y, w.y, acc[3].y);
      }
    }
    #pragma unroll
    for (int i = 0; i < 4; ++i){
      int r = row0 + rg * 4 + i;
      ((float2*)C)[(size_t)r * 64 + lane] = acc[i];
      float e1 = acc[i].x * as2.x + acc[i].y * as2.y;
      float e2 = acc[i].x * ad2.x + acc[i].y * ad2.y;
      #pragma unroll
      for (int o = 32; o; o >>= 1){ e1 += __shfl_xor(e1, o); e2 += __shfl_xor(e2, o); }
      if (lane == 0){ es[r] = e1; ed[r] = e2; }
    }
  }
}

// ---- per-graph counting sort by dst + inline dedupe-for-next-layer; one block/graph ----
__device__ void dev_csr(SM& sm, const int* __restrict__ src0, const int* __restrict__ dst0,
                        const unsigned char* __restrict__ maskIn,
                        int* __restrict__ csr_src, int* __restrict__ row_start,
                        int* __restrict__ row_cnt, int shift, int Npg,
                        unsigned char* __restrict__ maskOut, unsigned int* __restrict__ bitmap,
                        int shiftN, int log2NpgN, int g){
  int t = threadIdx.x;
  int ebase = g * EPG;
  unsigned int* bmg = nullptr;
  if (bitmap){
    int words = 1 << (2 * log2NpgN - 5);
    bmg = bitmap + (size_t)g * words;
    for (int i = t; i < words; i += NTHR) bmg[i] = 0;
  }
  if (t < Npg) sm.c.cnt[t] = 0;
  __syncthreads();
  unsigned keep = 0;
  #pragma unroll
  for (int k = 0; k < 8; ++k){
    int e = ebase + t + k * NTHR;
    int sv = src0[e], dv = dst0[e];
    bool act = maskIn ? (maskIn[e] != 0) : (sv != dv);
    if (act){
      keep |= (1u << k);
      atomicAdd(&sm.c.cnt[(dv >> shift) & (Npg - 1)], 1);
    }
    if (maskOut){
      unsigned char m2 = 0;
      if (act){
        int s2 = sv >> shiftN, d2 = dv >> shiftN;
        if (s2 != d2){
          int NpgN = 1 << log2NpgN;
          unsigned key = ((unsigned)(s2 & (NpgN - 1)) << log2NpgN) | (unsigned)(d2 & (NpgN - 1));
          unsigned bit = 1u << (key & 31u);
          unsigned old = atomicOr(&bmg[key >> 5], bit);
          m2 = (old & bit) ? 0 : 1;
        }
      }
      maskOut[e] = m2;
    }
  }
  __syncthreads();
  int c = (t < Npg) ? sm.c.cnt[t] : 0;
  int lane = t & 63, w = t >> 6;
  int v = c;
  #pragma unroll
  for (int o = 1; o < 64; o <<= 1){
    int u = __shfl_up(v, o);
    if (lane >= o) v += u;
  }
  if (lane == 63) sm.c.wsum[w] = v;
  __syncthreads();
  if (t == 0){
    int run = 0;
    #pragma unroll
    for (int i = 0; i < 16; ++i){ int x = sm.c.wsum[i]; sm.c.wsum[i] = run; run += x; }
  }
  __syncthreads();
  int excl = v - c + sm.c.wsum[w];
  if (t < Npg){
    sm.c.pos[t] = excl;
    row_start[g * Npg + t] = ebase + excl;
    row_cnt[g * Npg + t]   = c;
  }
  __syncthreads();
  #pragma unroll
  for (int k = 0; k < 8; ++k){
    if (keep & (1u << k)){
      int e = ebase + t + k * NTHR;
      int d = (dst0[e] >> shift) & (Npg - 1);
      int p = atomicAdd(&sm.c.pos[d], 1);
      csr_src[ebase + p] = src0[e] >> shift;
    }
  }
}

// ---- one GAT node (softmax over neighbors + self loop), returns relu(agg+bias) ----
__device__ float2 dev_gat_node(const float2* __restrict__ h2, const float* __restrict__ es,
                               const float* __restrict__ ed, const int* __restrict__ csr_src,
                               const int* __restrict__ row_start, const int* __restrict__ row_cnt,
                               float2 bv, int n, int lane){
  int start = row_start[n];
  int cnt   = row_cnt[n];
  float edn = ed[n];
  float selfl = lrelu(es[n] + edn);
  float m_l = -1e30f, d_l = 0.f;
  for (int c0 = 0; c0 < cnt; c0 += 64){
    int j = c0 + lane;
    if (j < cnt){
      int s = csr_src[start + j];
      float l = lrelu(es[s] + edn);
      float mn = fmaxf(m_l, l);
      d_l = d_l * __expf(m_l - mn) + __expf(l - mn);
      m_l = mn;
    }
  }
  #pragma unroll
  for (int o = 32; o; o >>= 1){
    float m2 = __shfl_xor(m_l, o), d2 = __shfl_xor(d_l, o);
    float mn = fmaxf(m_l, m2);
    d_l = d_l * __expf(m_l - mn) + d2 * __expf(m2 - mn);
    m_l = mn;
  }
  float mf  = fmaxf(m_l, selfl);
  float den = d_l * __expf(m_l - mf) + __expf(selfl - mf);
  float sw  = __expf(selfl - mf);
  float2 hv = h2[(size_t)n * 64 + lane];
  float2 acc; acc.x = sw * hv.x; acc.y = sw * hv.y;
  for (int c0 = 0; c0 < cnt; c0 += 64){
    int j = c0 + lane;
    int s_j = 0; float w_j = 0.f;
    if (j < cnt){
      s_j = csr_src[start + j];
      w_j = __expf(lrelu(es[s_j] + edn) - mf);
    }
    int rem = min(64, cnt - c0);
    int k = 0;
    for (; k + 8 <= rem; k += 8){
      int ss[8]; float ww[8]; float2 hh[8];
      #pragma unroll
      for (int i = 0; i < 8; ++i){ ss[i] = __shfl(s_j, k + i); ww[i] = __shfl(w_j, k + i); }
      #pragma unroll
      for (int i = 0; i < 8; ++i) hh[i] = h2[(size_t)ss[i] * 64 + lane];
      #pragma unroll
      for (int i = 0; i < 8; ++i){
        acc.x = fmaf(ww[i], hh[i].x, acc.x);
        acc.y = fmaf(ww[i], hh[i].y, acc.y);
      }
    }
    for (; k < rem; ++k){
      int s = __shfl(s_j, k); float w = __shfl(w_j, k);
      float2 hh = h2[(size_t)s * 64 + lane];
      acc.x = fmaf(w, hh.x, acc.x);
      acc.y = fmaf(w, hh.y, acc.y);
    }
  }
  float inv = 1.f / den;
  return make_float2(fmaxf(acc.x * inv + bv.x, 0.f), fmaxf(acc.y * inv + bv.y, 0.f));
}

// ---- GAT + pool + BN partial, XCD-pinned; bn partials into this XCD's slice ----
__device__ void dev_gat(SM& sm, const float* __restrict__ h, const float* __restrict__ es,
                        const float* __restrict__ ed, const int* __restrict__ csr_src,
                        const int* __restrict__ rs, const int* __restrict__ rc,
                        const float* __restrict__ bias, float* __restrict__ xout,
                        float* __restrict__ bnp_x, int ppg, int x, int wl, int nw){
  int lane = threadIdx.x & 63, wave = threadIdx.x >> 6;
  const float2* h2 = (const float2*)h;
  float2 bv = ((const float2*)bias)[lane];
  float4 part = make_float4(0.f, 0.f, 0.f, 0.f);
  int wv = wl * 16 + wave;
  int lpairs = GPX * ppg;
  for (int lp = wv; lp < lpairs; lp += nw * 16){
    int g = x + 8 * (lp / ppg);
    int p = g * ppg + (lp % ppg);
    float2 o0 = dev_gat_node(h2, es, ed, csr_src, rs, rc, bv, 2 * p,     lane);
    float2 o1 = dev_gat_node(h2, es, ed, csr_src, rs, rc, bv, 2 * p + 1, lane);
    float2 pl; pl.x = fmaxf(o0.x, o1.x); pl.y = fmaxf(o0.y, o1.y);
    ((float2*)xout)[(size_t)p * 64 + lane] = pl;
    part.x += pl.x; part.y += pl.y; part.z += pl.x * pl.x; part.w += pl.y * pl.y;
  }
  sm.b.bnred[wave * 64 + lane] = part;
  __syncthreads();
  if (wave == 0){
    float4 a = sm.b.bnred[lane];
    #pragma unroll
    for (int w = 1; w < 16; ++w){
      float4 b = sm.b.bnred[w * 64 + lane];
      a.x += b.x; a.y += b.y; a.z += b.z; a.w += b.w;
    }
    atomicAdd(&bnp_x[2 * lane],           a.x);
    atomicAdd(&bnp_x[2 * lane + 1],       a.y);
    atomicAdd(&bnp_x[128 + 2 * lane],     a.z);
    atomicAdd(&bnp_x[128 + 2 * lane + 1], a.w);
  }
}

// ---- persistent mega-kernel: all 3 layers, 6 grid barriers, XCD-pinned work ----
__global__ __launch_bounds__(NTHR)
void mega(const float* __restrict__ x0, const float* __restrict__ W0,
          const float* __restrict__ W1, const float* __restrict__ W2,
          const float* __restrict__ attS, const float* __restrict__ attD,
          const float* __restrict__ bias,
          const int* __restrict__ src0, const int* __restrict__ dst0,
          float* Hbuf, float* Xbuf, float* es, float* ed,
          int* csr1, int* rs1, int* rc1,
          int* csr2, int* rs2, int* rc2,
          int* csr3, int* rs3, int* rc3,
          unsigned char* mask2, unsigned char* mask3,
          unsigned int* bitmap0, unsigned int* bitmap1,
          float* bnp, unsigned* flags, unsigned* rel, float* out){
  __shared__ SM sm;
  int blk = blockIdx.x;
  int x = blk & 7;            // XCD id heuristic (round-robin dispatch)
  // bnp layout: [layer][xcd][256]  (256 = 128 sums + 128 sumsqs)

  // P1: csr L1 (blocks 0..31, graph pinned to own XCD) || gemm L1 (32..255)
  if (blk < 32){
    int g = x + 8 * (blk >> 3);
    dev_csr(sm, src0, dst0, nullptr, csr1, rs1, rc1, 0, 1024, mask2, bitmap0, 1, 9, g);
  } else {
    if (blk == 32){
      for (int i = threadIdx.x; i < 3 * 8 * 256; i += NTHR) bnp[i] = 0.f;
    }
    dev_gemm<64>(sm, x0, W0, nullptr, 0.f, attS, attD, Hbuf, es, ed,
                 16, x, (blk >> 3) - 4, 28);
  }
  grid_barrier(flags, rel, 1);

  // P2: csr L2 (0..31) || gat L1 + pool + bn0 (32..255)
  if (blk < 32){
    int g = x + 8 * (blk >> 3);
    dev_csr(sm, src0, dst0, mask2, csr2, rs2, rc2, 1, 512, mask3, bitmap1, 2, 8, g);
  } else {
    dev_gat(sm, Hbuf, es, ed, csr1, rs1, rc1, bias, Xbuf, bnp + x * 256,
            512, x, (blk >> 3) - 4, 28);
  }
  grid_barrier(flags, rel, 2);

  // P3: csr L3 (0..31) || gemm L2 (32..255), bn from layer-1 partials
  if (blk < 32){
    int g = x + 8 * (blk >> 3);
    dev_csr(sm, src0, dst0, mask3, csr3, rs3, rc3, 2, 256, nullptr, nullptr, 0, 0, g);
  } else {
    dev_gemm<128>(sm, Xbuf, W1, bnp, 1.f / 16384.f, attS + 128, attD + 128,
                  Hbuf, es, ed, 8, x, (blk >> 3) - 4, 28);
  }
  grid_barrier(flags, rel, 3);

  // P4: gat L2 + pool + bn1 (all blocks)
  dev_gat(sm, Hbuf, es, ed, csr2, rs2, rc2, bias + 128, Xbuf, bnp + (8 + x) * 256,
          256, x, blk >> 3, 32);
  grid_barrier(flags, rel, 4);

  // P5: gemm L3 (all blocks; 16 tiles/XCD so waves with wl>=16 idle briefly)
  dev_gemm<128>(sm, Xbuf, W2, bnp + 8 * 256, 1.f / 8192.f, attS + 256, attD + 256,
                Hbuf, es, ed, 4, x, blk >> 3, 32);
  grid_barrier(flags, rel, 5);

  // P6: gat L3 + pool + bn2 (all blocks)
  dev_gat(sm, Hbuf, es, ed, csr3, rs3, rc3, bias + 256, Xbuf, bnp + (16 + x) * 256,
          128, x, blk >> 3, 32);
  grid_barrier(flags, rel, 6);

  // P7: final BatchNorm apply -> out, XCD-pinned rows (exactly 1 elem/thread)
  {
    const float* b2 = bnp + 16 * 256;
    int ii = (blk >> 3) * NTHR + threadIdx.x;    // 0..32767 within this XCD
    int row_l = ii >> 6;                          // 0..511 local row
    int g = x + 8 * (row_l >> 7);
    int row = g * 128 + (row_l & 127);
    int c2 = ii & 63;
    float s0 = 0.f, q0 = 0.f, s1 = 0.f, q1 = 0.f;
    #pragma unroll
    for (int xx = 0; xx < 8; ++xx){
      const float* b = b2 + xx * 256;
      s0 += b[2 * c2];     q0 += b[128 + 2 * c2];
      s1 += b[2 * c2 + 1]; q1 += b[128 + 2 * c2 + 1];
    }
    float mu0 = s0 * (1.f / 4096.f), mu1 = s1 * (1.f / 4096.f);
    float r0 = rsqrtf(q0 * (1.f / 4096.f) - mu0 * mu0 + EPS_BN);
    float r1 = rsqrtf(q1 * (1.f / 4096.f) - mu1 * mu1 + EPS_BN);
    float2 v = ((const float2*)Xbuf)[(size_t)row * 64 + c2];
    ((float2*)out)[(size_t)row * 64 + c2] =
        make_float2((v.x - mu0) * r0, (v.y - mu1) * r1);
  }
}

extern "C" void kernel_launch(void* const* d_in, const int* in_sizes, int n_in,
                              void* d_out, int out_size, void* d_ws, size_t ws_size,
                              hipStream_t stream){
  const float* x0   = (const float*)d_in[0];
  const float* W0   = (const float*)d_in[1];
  const float* W1   = (const float*)d_in[2];
  const float* W2   = (const float*)d_in[3];
  const float* attS = (const float*)d_in[4];
  const float* attD = (const float*)d_in[5];
  const float* bias = (const float*)d_in[6];
  const int*   src0 = (const int*)d_in[7];
  const int*   dst0 = src0 + E_TOTAL;
  float* out = (float*)d_out;

  char* ws = (char*)d_ws;
  float*         Hbuf    = (float*)(ws);                          // 16 MB
  float*         Xbuf    = (float*)(ws + (16u << 20));            //  8 MB
  float*         es      = (float*)(ws + (24u << 20));            // 128 KB
  float*         ed      = (float*)(ws + (24u << 20) + (128u << 10));
  int*           csr1    = (int*)  (ws + (25u << 20));            // 1 MB
  int*           csr2    = (int*)  (ws + (26u << 20));            // 1 MB
  int*           csr3    = (int*)  (ws + (27u << 20));            // 1 MB
  int*           rs1     = (int*)  (ws + (28u << 20));            // 128 KB each
  int*           rc1     = (int*)  (ws + (28u << 20) + 1 * (128u << 10));
  int*           rs2     = (int*)  (ws + (28u << 20) + 2 * (128u << 10));
  int*           rc2     = (int*)  (ws + (28u << 20) + 3 * (128u << 10));
  int*           rs3     = (int*)  (ws + (28u << 20) + 4 * (128u << 10));
  int*           rc3     = (int*)  (ws + (28u << 20) + 5 * (128u << 10));
  unsigned char* mask2   = (unsigned char*)(ws + (29u << 20));           // 256 KB
  unsigned char* mask3   = (unsigned char*)(ws + (29u << 20) + (256u << 10));
  unsigned int*  bitmap0 = (unsigned int*)(ws + (30u << 20));            // 1 MB
  unsigned int*  bitmap1 = (unsigned int*)(ws + (31u << 20));            // 256 KB
  unsigned*      flags   = (unsigned*)(ws + (31u << 20) + (256u << 10)); // 16 KB
  unsigned*      rel     = (unsigned*)(ws + (31u << 20) + (272u << 10)); // 64 B
  float*         bnp     = (float*)  (ws + (31u << 20) + (273u << 10));  // 3*8*256 f

  hipMemsetAsync(flags, 0, (16u << 10) + 64, stream);   // flags + rel; bnp zeroed in-kernel
  hipLaunchKernelGGL(mega, dim3(NBLK), dim3(NTHR), 0, stream,
                     x0, W0, W1, W2, attS, attD, bias, src0, dst0,
                     Hbuf, Xbuf, es, ed,
                     csr1, rs1, rc1, csr2, rs2, rc2, csr3, rs3, rc3,
                     mask2, mask3, bitmap0, bitmap1, bnp, flags, rel, out);
}